// Round 1
// baseline (202.225 us; speedup 1.0000x reference)
//
#include <hip/hip_runtime.h>
#include <math.h>

#define H 256
#define L 50
#define V 50257

__device__ __forceinline__ float dot4(float4 a, float4 b) {
    return a.x * b.x + a.y * b.y + a.z * b.z + a.w * b.w;
}

__device__ __forceinline__ float wave_reduce_sum(float v) {
#pragma unroll
    for (int m = 32; m >= 1; m >>= 1) v += __shfl_xor(v, m, 64);
    return v;
}

__device__ __forceinline__ float wave_reduce_max(float v) {
#pragma unroll
    for (int m = 32; m >= 1; m >>= 1) v = fmaxf(v, __shfl_xor(v, m, 64));
    return v;
}

__device__ __forceinline__ float sigmoidf(float x) { return 1.0f / (1.0f + __expf(-x)); }

// ---------------------------------------------------------------------------
// Kernel 1: embedding gather + attention scores + softmax + applied vector.
// Single block of 256 threads (all data touched ~150 KB).
// Writes cat = [e | applied] (512 floats) to ws, aw (50) to d_out tail.
// ---------------------------------------------------------------------------
__global__ __launch_bounds__(256) void k_attn(
    const int* __restrict__ token, const float* __restrict__ hidden,
    const float* __restrict__ enc, const float* __restrict__ emb,
    const float* __restrict__ attn_W, const float* __restrict__ attn_b,
    float* __restrict__ ws_cat, float* __restrict__ out_aw)
{
    __shared__ float s_vec[2 * H];  // [e | h0]
    __shared__ float s_scores[L];
    __shared__ float s_aw[L];
    int t = threadIdx.x;
    int tok = token[0];
    s_vec[t] = emb[(size_t)tok * H + t];
    s_vec[H + t] = hidden[t];
    __syncthreads();

    int wid = t >> 6, lane = t & 63;
    // scores: wave-per-row over 50 rows of attn_W (50 x 512)
    for (int l = wid; l < L; l += 4) {
        float acc = 0.f;
#pragma unroll
        for (int c = 0; c < 8; ++c)
            acc += attn_W[l * 2 * H + c * 64 + lane] * s_vec[c * 64 + lane];
        acc = wave_reduce_sum(acc);
        if (lane == 0) s_scores[l] = fmaxf(acc + attn_b[l], 0.f);  // relu
    }
    __syncthreads();

    // softmax over 50 in wave 0
    if (t < 64) {
        float v = (t < L) ? s_scores[t] : -INFINITY;
        float m = wave_reduce_max(v);
        float e = (t < L) ? __expf(v - m) : 0.f;
        float s = wave_reduce_sum(e);
        float aw = e / s;
        if (t < L) { s_aw[t] = aw; out_aw[t] = aw; }
    }
    __syncthreads();

    // applied[j] = sum_l aw[l] * enc[l][j]  (coalesced over j = t)
    float acc = 0.f;
    for (int l = 0; l < L; ++l) acc += s_aw[l] * enc[l * H + t];
    ws_cat[t] = s_vec[t];      // e
    ws_cat[H + t] = acc;       // applied
}

// ---------------------------------------------------------------------------
// Kernel 2: x = relu(comb_W @ cat + comb_b). 256 rows of 512. Wave-per-row.
// ---------------------------------------------------------------------------
__global__ __launch_bounds__(256) void k_comb(
    const float* __restrict__ comb_W, const float* __restrict__ comb_b,
    const float* __restrict__ ws_cat, float* __restrict__ ws_x)
{
    int t = threadIdx.x, wid = t >> 6, lane = t & 63;
    int row = blockIdx.x * 4 + wid;  // 0..255
    const float4* W4 = (const float4*)(comb_W + (size_t)row * 2 * H);
    const float4* c4 = (const float4*)ws_cat;
    float acc = dot4(W4[lane], c4[lane]) + dot4(W4[lane + 64], c4[lane + 64]);
    acc = wave_reduce_sum(acc);
    if (lane == 0) ws_x[row] = fmaxf(acc + comb_b[row], 0.f);
}

// ---------------------------------------------------------------------------
// Kernel 3: bidirectional GRU cells (hf, hb). Wave per (dir, hidden-index).
// 512 waves -> 128 blocks. Each wave: 6 length-256 dots (float4/lane, 1 KB
// coalesced row loads) + butterfly reduces, then gate math on all lanes.
// ---------------------------------------------------------------------------
__global__ __launch_bounds__(256) void k_gru_fb(
    const float* __restrict__ ws_x, const float* __restrict__ hidden,
    const float* __restrict__ w_ih_f, const float* __restrict__ w_hh_f,
    const float* __restrict__ b_ih_f, const float* __restrict__ b_hh_f,
    const float* __restrict__ w_ih_b, const float* __restrict__ w_hh_b,
    const float* __restrict__ b_ih_b, const float* __restrict__ b_hh_b,
    float* __restrict__ ws_hf, float* __restrict__ ws_hb)
{
    int t = threadIdx.x, wid = t >> 6, lane = t & 63;
    int g = blockIdx.x * 4 + wid;  // 0..511
    int dir = g >> 8;
    int j = g & 255;
    const float* w_ih = dir ? w_ih_b : w_ih_f;
    const float* w_hh = dir ? w_hh_b : w_hh_f;
    const float* b_ih = dir ? b_ih_b : b_ih_f;
    const float* b_hh = dir ? b_hh_b : b_hh_f;
    float* outp = dir ? ws_hb : ws_hf;

    const float4* x4 = (const float4*)ws_x;
    const float4* h4 = (const float4*)hidden;
    float4 xv = x4[lane];
    float4 hv = h4[lane];
    float gi[3], gh[3];
#pragma unroll
    for (int k = 0; k < 3; ++k) {
        int row = k * H + j;
        const float4* wi4 = (const float4*)(w_ih + (size_t)row * H);
        const float4* wh4 = (const float4*)(w_hh + (size_t)row * H);
        gi[k] = wave_reduce_sum(dot4(wi4[lane], xv)) + b_ih[row];
        gh[k] = wave_reduce_sum(dot4(wh4[lane], hv)) + b_hh[row];
    }
    if (lane == 0) {
        float r = sigmoidf(gi[0] + gh[0]);
        float z = sigmoidf(gi[1] + gh[1]);
        float n = tanhf(gi[2] + r * gh[2]);
        outp[j] = (1.f - z) * n + z * hidden[j];
    }
}

// ---------------------------------------------------------------------------
// Kernels 4/5: generic GRU cell, wave per hidden index (64 blocks).
// If hb != nullptr, the recurrent state is 0.5*(ha + hb) (torch.mean of the
// two directions); else it's ha.
// ---------------------------------------------------------------------------
__global__ __launch_bounds__(256) void k_gru(
    const float* __restrict__ xvec, const float* __restrict__ ha,
    const float* __restrict__ hb,
    const float* __restrict__ w_ih, const float* __restrict__ w_hh,
    const float* __restrict__ b_ih, const float* __restrict__ b_hh,
    float* __restrict__ outp)
{
    int t = threadIdx.x, wid = t >> 6, lane = t & 63;
    int j = blockIdx.x * 4 + wid;  // 0..255
    const float4* x4 = (const float4*)xvec;
    const float4* a4 = (const float4*)ha;
    float4 xv = x4[lane];
    float4 hv = a4[lane];
    float hj;
    if (hb) {
        const float4* b4 = (const float4*)hb;
        float4 bv = b4[lane];
        hv.x = 0.5f * (hv.x + bv.x);
        hv.y = 0.5f * (hv.y + bv.y);
        hv.z = 0.5f * (hv.z + bv.z);
        hv.w = 0.5f * (hv.w + bv.w);
        hj = 0.5f * (ha[j] + hb[j]);
    } else {
        hj = ha[j];
    }
    float gi[3], gh[3];
#pragma unroll
    for (int k = 0; k < 3; ++k) {
        int row = k * H + j;
        const float4* wi4 = (const float4*)(w_ih + (size_t)row * H);
        const float4* wh4 = (const float4*)(w_hh + (size_t)row * H);
        gi[k] = wave_reduce_sum(dot4(wi4[lane], xv)) + b_ih[row];
        gh[k] = wave_reduce_sum(dot4(wh4[lane], hv)) + b_hh[row];
    }
    if (lane == 0) {
        float r = sigmoidf(gi[0] + gh[0]);
        float z = sigmoidf(gi[1] + gh[1]);
        float n = tanhf(gi[2] + r * gh[2]);
        outp[j] = (1.f - z) * n + z * hj;
    }
}

// ---------------------------------------------------------------------------
// Kernel 6: logits[v] = out_W[v,:] . h1 + out_b[v]. Wave-per-row, grid-stride.
// Row = 256 floats = 64 float4 = exactly one float4 per lane (1 KB coalesced).
// This is the HBM-dominant kernel (51.5 MB of out_W).
// ---------------------------------------------------------------------------
__global__ __launch_bounds__(256) void k_logits(
    const float* __restrict__ out_W, const float* __restrict__ out_b,
    const float* __restrict__ h1, float* __restrict__ logits)
{
    int t = threadIdx.x, wid = t >> 6, lane = t & 63;
    int wave = blockIdx.x * 4 + wid;
    int nw = gridDim.x * 4;
    const float4* h4 = (const float4*)h1;
    float4 hv = h4[lane];
    for (int v = wave; v < V; v += nw) {
        const float4* W4 = (const float4*)(out_W + (size_t)v * H);
        float acc = wave_reduce_sum(dot4(W4[lane], hv));
        if (lane == 0) logits[v] = acc + out_b[v];
    }
}

// ---------------------------------------------------------------------------
// Kernel 7: lse = max + log(sum(exp(logit - max))) over V. Single block.
// ---------------------------------------------------------------------------
__global__ __launch_bounds__(1024) void k_lse(
    const float* __restrict__ logits, float* __restrict__ ws_lse)
{
    __shared__ float red_m[16];
    __shared__ float red_s[16];
    int t = threadIdx.x, wid = t >> 6, lane = t & 63;
    float m = -INFINITY;
    for (int i = t; i < V; i += 1024) m = fmaxf(m, logits[i]);
    m = wave_reduce_max(m);
    if (lane == 0) red_m[wid] = m;
    __syncthreads();
    if (t == 0) {
        float v = red_m[0];
        for (int k = 1; k < 16; ++k) v = fmaxf(v, red_m[k]);
        red_m[0] = v;
    }
    __syncthreads();
    float gmax = red_m[0];
    float s = 0.f;
    for (int i = t; i < V; i += 1024) s += __expf(logits[i] - gmax);
    s = wave_reduce_sum(s);
    if (lane == 0) red_s[wid] = s;
    __syncthreads();
    if (t == 0) {
        float tot = 0.f;
        for (int k = 0; k < 16; ++k) tot += red_s[k];
        ws_lse[0] = gmax + logf(tot);
    }
}

// ---------------------------------------------------------------------------
// Kernel 8: logp = logits - lse, in place in d_out.
// ---------------------------------------------------------------------------
__global__ __launch_bounds__(256) void k_sub(
    float* __restrict__ logits, const float* __restrict__ ws_lse)
{
    int i = blockIdx.x * blockDim.x + threadIdx.x;
    if (i < V) logits[i] -= ws_lse[0];
}

extern "C" void kernel_launch(void* const* d_in, const int* in_sizes, int n_in,
                              void* d_out, int out_size, void* d_ws, size_t ws_size,
                              hipStream_t stream)
{
    const int*   token  = (const int*)d_in[0];
    const float* hidden = (const float*)d_in[1];
    const float* enc    = (const float*)d_in[2];
    const float* emb    = (const float*)d_in[3];
    const float* attn_W = (const float*)d_in[4];
    const float* attn_b = (const float*)d_in[5];
    const float* comb_W = (const float*)d_in[6];
    const float* comb_b = (const float*)d_in[7];
    const float* w_ih_f = (const float*)d_in[8];
    const float* w_hh_f = (const float*)d_in[9];
    const float* b_ih_f = (const float*)d_in[10];
    const float* b_hh_f = (const float*)d_in[11];
    const float* w_ih_b = (const float*)d_in[12];
    const float* w_hh_b = (const float*)d_in[13];
    const float* b_ih_b = (const float*)d_in[14];
    const float* b_hh_b = (const float*)d_in[15];
    const float* w_ih_g = (const float*)d_in[16];
    const float* w_hh_g = (const float*)d_in[17];
    const float* b_ih_g = (const float*)d_in[18];
    const float* b_hh_g = (const float*)d_in[19];
    const float* out_W  = (const float*)d_in[20];
    const float* out_b  = (const float*)d_in[21];

    float* out = (float*)d_out;  // layout: [V logp | H h2 | L aw]
    float* ws  = (float*)d_ws;
    float* ws_cat = ws;          // 512 floats
    float* ws_x   = ws + 512;    // 256
    float* ws_hf  = ws + 768;    // 256
    float* ws_hb  = ws + 1024;   // 256
    float* ws_h1  = ws + 1280;   // 256
    float* ws_lse = ws + 1536;   // 1

    k_attn<<<1, 256, 0, stream>>>(token, hidden, enc, emb, attn_W, attn_b,
                                  ws_cat, out + V + H);
    k_comb<<<64, 256, 0, stream>>>(comb_W, comb_b, ws_cat, ws_x);
    k_gru_fb<<<128, 256, 0, stream>>>(ws_x, hidden,
                                      w_ih_f, w_hh_f, b_ih_f, b_hh_f,
                                      w_ih_b, w_hh_b, b_ih_b, b_hh_b,
                                      ws_hf, ws_hb);
    // h1 = gru(hf, mean(hf,hb))
    k_gru<<<64, 256, 0, stream>>>(ws_hf, ws_hf, ws_hb,
                                  w_ih_g, w_hh_g, b_ih_g, b_hh_g, ws_h1);
    // h2 = gru(hb, h1) -> second output
    k_gru<<<64, 256, 0, stream>>>(ws_hb, ws_h1, nullptr,
                                  w_ih_g, w_hh_g, b_ih_g, b_hh_g, out + V);
    k_logits<<<3142, 256, 0, stream>>>(out_W, out_b, ws_h1, out);
    k_lse<<<1, 1024, 0, stream>>>(out, ws_lse);
    k_sub<<<197, 256, 0, stream>>>(out, ws_lse);
}